// Round 5
// baseline (138.931 us; speedup 1.0000x reference)
//
#include <hip/hip_runtime.h>
#include <math.h>

#define BB 4
#define SQL 512
#define SKL 512
#define HH 256
#define AA 128

// 2 * log2(e): Qt/Kt pre-scaled so the score loop feeds v_exp_f32 (2^x) directly.
#define PRESCALE 2.8853900817779268f

__device__ inline void fma4(float4& a, float s, const float4& b) {
    a.x = fmaf(s, b.x, a.x); a.y = fmaf(s, b.y, a.y);
    a.z = fmaf(s, b.z, a.z); a.w = fmaf(s, b.w, a.w);
}

__device__ inline unsigned short f_to_bf16(float f) {   // round-to-nearest-even
    unsigned u = __float_as_uint(f);
    return (unsigned short)((u + 0x7fffu + ((u >> 16) & 1u)) >> 16);
}
__device__ inline float4 bf16x4_to_f4(uint2 u) {
    float4 r;
    r.x = __uint_as_float(u.x << 16);
    r.y = __uint_as_float(u.x & 0xffff0000u);
    r.z = __uint_as_float(u.y << 16);
    r.w = __uint_as_float(u.y & 0xffff0000u);
    return r;
}

// ---------------------------------------------------------------------------
// Kernel 1 "prep": Qt = PRESCALE*(Q@W_q), Kt = PRESCALE*(K@W_k), VW = bf16(V@W_o).
// grid 512 x 256 thr. Block = 16 output rows x 128 output cols.
// W chunks (64x128, 32 KB) are PREFETCHED into registers during the previous
// chunk's compute -> the global->LDS staging latency is off the critical path
// (the R4 latency killer at 2 blocks/CU).
// ---------------------------------------------------------------------------
__global__ __launch_bounds__(256) void prep_kernel(
    const float* __restrict__ Q, const float* __restrict__ K,
    const float* __restrict__ V,
    const float* __restrict__ Wq, const float* __restrict__ Wk,
    const float* __restrict__ Wo,
    float* __restrict__ Qt, float* __restrict__ Kt,
    unsigned short* __restrict__ VW)
{
    __shared__ float rows[16 * HH];    // 16 KB
    __shared__ float wl[64 * 128];     // 32 KB
    int tid = threadIdx.x;
    int bid = blockIdx.x;

    const float* X; const float* W;
    int ldW, col0, r0; float scale;
    if (bid < 128)      { X=Q; W=Wq; ldW=AA; col0=0; r0=bid*16;       scale=PRESCALE; }
    else if (bid < 256) { X=K; W=Wk; ldW=AA; col0=0; r0=(bid-128)*16; scale=PRESCALE; }
    else { int b2=bid-256; X=V; W=Wo; ldW=HH; col0=(b2&1)*128; r0=(b2>>1)*16; scale=1.0f; }

    // stage 16 input rows (4096 floats, contiguous, float4)
    {
        const float4* Xv = (const float4*)(X + (size_t)r0 * HH);
        float4* rv = (float4*)rows;
        rv[tid]       = Xv[tid];
        rv[tid + 256] = Xv[tid + 256];
        rv[tid + 512] = Xv[tid + 512];
        rv[tid + 768] = Xv[tid + 768];
    }

    // prefetch W chunk 0 into registers
    float4 wpf[8];
    {
        const float* Wb = W + col0;
        #pragma unroll
        for (int it = 0; it < 8; ++it) {
            int l = tid + it * 256;
            wpf[it] = *(const float4*)(Wb + (size_t)(l >> 5) * ldW + ((l & 31) << 2));
        }
    }

    int r  = tid >> 5;       // rows r and r+8
    int c4 = tid & 31;       // float4 output col
    float4 accA = {0.f,0.f,0.f,0.f}, accB = {0.f,0.f,0.f,0.f};

    for (int ch = 0; ch < 4; ++ch) {
        __syncthreads();     // rows staged / previous wl reads done
        {   // write prefetched W chunk to LDS, then issue next chunk's loads
            float4* wv = (float4*)wl;
            #pragma unroll
            for (int it = 0; it < 8; ++it) wv[tid + it * 256] = wpf[it];
            if (ch < 3) {
                const float* Wb = W + (size_t)((ch + 1) * 64) * ldW + col0;
                #pragma unroll
                for (int it = 0; it < 8; ++it) {
                    int l = tid + it * 256;
                    wpf[it] = *(const float4*)(Wb + (size_t)(l >> 5) * ldW + ((l & 31) << 2));
                }
            }
        }
        __syncthreads();
        const float* rrowA = rows + r * HH + ch * 64;
        const float* rrowB = rows + (r + 8) * HH + ch * 64;
        #pragma unroll 4
        for (int h4 = 0; h4 < 16; ++h4) {
            float4 ra = *(const float4*)(rrowA + h4 * 4);       // broadcast b128
            float4 rb = *(const float4*)(rrowB + h4 * 4);
            const float* wbase = wl + (h4 * 4) * 128 + (c4 << 2);
            float4 w0 = *(const float4*)(wbase);                // contiguous b128
            float4 w1 = *(const float4*)(wbase + 128);
            float4 w2 = *(const float4*)(wbase + 256);
            float4 w3 = *(const float4*)(wbase + 384);
            fma4(accA, ra.x, w0); fma4(accA, ra.y, w1);
            fma4(accA, ra.z, w2); fma4(accA, ra.w, w3);
            fma4(accB, rb.x, w0); fma4(accB, rb.y, w1);
            fma4(accB, rb.z, w2); fma4(accB, rb.w, w3);
        }
    }

    if (bid < 256) {         // Qt / Kt: fp32, prescaled
        float* Y = (bid < 128) ? Qt : Kt;
        accA.x *= scale; accA.y *= scale; accA.z *= scale; accA.w *= scale;
        accB.x *= scale; accB.y *= scale; accB.z *= scale; accB.w *= scale;
        *(float4*)(Y + (size_t)(r0 + r)     * AA + (c4 << 2)) = accA;
        *(float4*)(Y + (size_t)(r0 + r + 8) * AA + (c4 << 2)) = accB;
    } else {                 // VW: bf16 (halves the epilogue's L2 traffic)
        ushort4 sa = { f_to_bf16(accA.x), f_to_bf16(accA.y),
                       f_to_bf16(accA.z), f_to_bf16(accA.w) };
        ushort4 sb = { f_to_bf16(accB.x), f_to_bf16(accB.y),
                       f_to_bf16(accB.z), f_to_bf16(accB.w) };
        *(ushort4*)(VW + (size_t)(r0 + r)     * HH + col0 + (c4 << 2)) = sa;
        *(ushort4*)(VW + (size_t)(r0 + r + 8) * HH + col0 + (c4 << 2)) = sb;
    }
}

// ---------------------------------------------------------------------------
// Kernel 2: fused scores + softmax + (weights @ VW + b_o).
// grid = B*SQ/2 = 1024 blocks x 256 thr (4 blocks/CU).
//   score[q][k] = S_all - sum_a 2*v[a] * rcp(2^(Qt[q][a]+Kt[k][a]) + 1)
// Trans reduction: e^{2x1} = e^{2x0} * d[j],  d[j] = 2^(Qt1[a]-Qt0[a])
// (k-independent, precomputed) -> 3 trans per q-pair instead of 4.
// Kt chunk (c+1) PREFETCHED into registers during chunk c's compute.
// Softmax: 4 waves = (2 rows) x (2 halves). Epilogue: bf16 VW, wave k-quarter.
// ---------------------------------------------------------------------------
__global__ __launch_bounds__(256) void score_kernel(
    const float* __restrict__ Qt, const float* __restrict__ Kt,
    const float* __restrict__ v,  const unsigned short* __restrict__ VW,
    const float* __restrict__ bo,
    float* __restrict__ weights,  float* __restrict__ out)
{
    __shared__ float score[2][SKL];      // 4 KB
    __shared__ float pout[4][2][HH];     // 8 KB
    __shared__ float pm[2][2], ps[2][2];

    int tid = threadIdx.x;
    int b  = blockIdx.x >> 8;            // 256 blocks per batch
    int q0 = (blockIdx.x & 255) << 1;    // 2 q-rows per block
    int ag = tid & 7;                    // a-range [16ag, 16ag+16)
    int kl = tid >> 3;                   // k within 32-chunk

    // register caches: Qt row0 (prescaled), d = 2^(q1-q0), 2*v
    float qreg0[16], dreg[16], v2reg[16];
    {
        const float4* vp  = (const float4*)(v + ag * 16);
        const float4* qp0 = (const float4*)(Qt + (size_t)(b * SQL + q0)     * AA + ag * 16);
        const float4* qp1 = (const float4*)(Qt + (size_t)(b * SQL + q0 + 1) * AA + ag * 16);
        #pragma unroll
        for (int j4 = 0; j4 < 4; ++j4) {
            float4 vv4 = vp[j4];
            float4 a0  = qp0[j4];
            float4 a1  = qp1[j4];
            *(float4*)&qreg0[j4 * 4] = a0;
            dreg[j4*4+0] = __builtin_amdgcn_exp2f(a1.x - a0.x);
            dreg[j4*4+1] = __builtin_amdgcn_exp2f(a1.y - a0.y);
            dreg[j4*4+2] = __builtin_amdgcn_exp2f(a1.z - a0.z);
            dreg[j4*4+3] = __builtin_amdgcn_exp2f(a1.w - a0.w);
            v2reg[j4*4+0] = 2.0f * vv4.x;
            v2reg[j4*4+1] = 2.0f * vv4.y;
            v2reg[j4*4+2] = 2.0f * vv4.z;
            v2reg[j4*4+3] = 2.0f * vv4.w;
        }
    }

    // S_all = sum_a v[a]: local partial then xor-reduce over the 8 ag-lanes
    float S_all;
    {
        float ls = 0.f;
        #pragma unroll
        for (int j = 0; j < 16; ++j) ls += v2reg[j];
        ls += __shfl_xor(ls, 1);
        ls += __shfl_xor(ls, 2);
        ls += __shfl_xor(ls, 4);
        S_all = 0.5f * ls;               // ls = 2*sum(v)
    }

    // ---- main loop: 16 chunks x 32 k-rows; next-chunk Kt prefetched ----
    const float4* kp = (const float4*)(Kt + (size_t)(b * SKL + kl) * AA + ag * 16);
    float4 n0 = kp[0], n1 = kp[1], n2 = kp[2], n3 = kp[3];
    for (int c = 0; c < 16; ++c) {
        float kt[16];
        *(float4*)&kt[0]  = n0;
        *(float4*)&kt[4]  = n1;
        *(float4*)&kt[8]  = n2;
        *(float4*)&kt[12] = n3;
        if (c < 15) {
            const float4* np = kp + (size_t)(c + 1) * 32 * (AA / 4);
            n0 = np[0]; n1 = np[1]; n2 = np[2]; n3 = np[3];
        }

        float p0 = 0.f, p1 = 0.f;
        #pragma unroll
        for (int j = 0; j < 16; ++j) {
            float x0 = qreg0[j] + kt[j];
            float e0 = __builtin_amdgcn_exp2f(x0);
            float e1 = e0 * dreg[j];               // = 2^(q1+kv)
            float r0 = __builtin_amdgcn_rcpf(e0 + 1.0f);
            float r1 = __builtin_amdgcn_rcpf(e1 + 1.0f);
            p0 = fmaf(v2reg[j], r0, p0);
            p1 = fmaf(v2reg[j], r1, p1);
        }
        p0 += __shfl_xor(p0, 1); p1 += __shfl_xor(p1, 1);
        p0 += __shfl_xor(p0, 2); p1 += __shfl_xor(p1, 2);
        p0 += __shfl_xor(p0, 4); p1 += __shfl_xor(p1, 4);
        if (ag == 0) {
            int k = c * 32 + kl;
            score[0][k] = S_all - p0;
            score[1][k] = S_all - p1;
        }
    }
    __syncthreads();

    // ---- softmax: 4 waves = (row qi) x (half) ; each wave: 256 k via float4
    int wave = tid >> 6, lane = tid & 63;
    int qi = wave & 1, half = wave >> 1;
    {
        float4* srow = (float4*)&score[qi][half * 256];   // 64 float4
        float4 sv = srow[lane];
        float m = fmaxf(fmaxf(sv.x, sv.y), fmaxf(sv.z, sv.w));
        #pragma unroll
        for (int off = 32; off; off >>= 1) m = fmaxf(m, __shfl_xor(m, off));
        if (lane == 0) pm[qi][half] = m;
        __syncthreads();
        float M = fmaxf(pm[qi][0], pm[qi][1]);
        float4 e;
        e.x = __builtin_amdgcn_exp2f((sv.x - M) * 1.44269504f);
        e.y = __builtin_amdgcn_exp2f((sv.y - M) * 1.44269504f);
        e.z = __builtin_amdgcn_exp2f((sv.z - M) * 1.44269504f);
        e.w = __builtin_amdgcn_exp2f((sv.w - M) * 1.44269504f);
        float s = (e.x + e.y) + (e.z + e.w);
        #pragma unroll
        for (int off = 32; off; off >>= 1) s += __shfl_xor(s, off);
        if (lane == 0) ps[qi][half] = s;
        __syncthreads();
        float rinv = 1.0f / (ps[qi][0] + ps[qi][1]);
        float4 w4 = { e.x * rinv, e.y * rinv, e.z * rinv, e.w * rinv };
        srow[lane] = w4;                                   // for epilogue
        *(float4*)(weights + (size_t)(b * SQL + q0 + qi) * SKL + half * 256 + (lane << 2)) = w4;
    }
    __syncthreads();

    // ---- epilogue: wave w owns k in [128w, 128w+128); VW is bf16
    {
        const uint2* VWb = (const uint2*)(VW + (size_t)b * SKL * HH);
        float4 a0 = {0,0,0,0}, a1 = {0,0,0,0};
        int kbase = wave * 128;
        #pragma unroll 4
        for (int k = 0; k < 128; ++k) {
            int kk = kbase + k;
            uint2 u = VWb[(size_t)kk * (HH / 4) + lane];   // 8B/lane, coalesced
            float4 vw4 = bf16x4_to_f4(u);
            float w0 = score[0][kk];                       // wave-uniform broadcast
            float w1 = score[1][kk];
            fma4(a0, w0, vw4);
            fma4(a1, w1, vw4);
        }
        *(float4*)&pout[wave][0][lane << 2] = a0;
        *(float4*)&pout[wave][1][lane << 2] = a1;
    }
    __syncthreads();
    {
        int h = tid;
        float bias = bo[h];
        #pragma unroll
        for (int qi2 = 0; qi2 < 2; ++qi2) {
            float s = bias + pout[0][qi2][h] + pout[1][qi2][h]
                           + pout[2][qi2][h] + pout[3][qi2][h];
            out[(size_t)(b * SQL + q0 + qi2) * HH + h] = s;
        }
    }
}

// ---------------------------------------------------------------------------
extern "C" void kernel_launch(void* const* d_in, const int* in_sizes, int n_in,
                              void* d_out, int out_size, void* d_ws, size_t ws_size,
                              hipStream_t stream)
{
    const float* Q  = (const float*)d_in[0];
    const float* K  = (const float*)d_in[1];
    const float* V  = (const float*)d_in[2];
    const float* Wq = (const float*)d_in[3];
    const float* Wk = (const float*)d_in[4];
    const float* v  = (const float*)d_in[5];
    const float* Wo = (const float*)d_in[6];
    const float* bo = (const float*)d_in[7];

    float* out     = (float*)d_out;                   // (B,SQ,H) = 524288
    float* weights = out + (size_t)BB * SQL * HH;     // (B,SQ,SK) = 1048576

    float* Qt = (float*)d_ws;                         // 262144 floats
    float* Kt = Qt + (size_t)BB * SQL * AA;           // 262144 floats
    unsigned short* VW = (unsigned short*)(Kt + (size_t)BB * SKL * AA); // 524288 bf16

    prep_kernel <<<512, 256, 0, stream>>>(Q, K, V, Wq, Wk, Wo, Qt, Kt, VW);
    score_kernel<<<1024, 256, 0, stream>>>(Qt, Kt, v, VW, bo, weights, out);
}

// Round 6
// 130.807 us; speedup vs baseline: 1.0621x; 1.0621x over previous
//
#include <hip/hip_runtime.h>
#include <math.h>

#define BB 4
#define SQL 512
#define SKL 512
#define HH 256
#define AA 128

// 2 * log2(e): Qt/Kt pre-scaled so the score loop feeds v_exp_f32 (2^x) directly.
#define PRESCALE 2.8853900817779268f

__device__ inline void fma4(float4& a, float s, const float4& b) {
    a.x = fmaf(s, b.x, a.x); a.y = fmaf(s, b.y, a.y);
    a.z = fmaf(s, b.z, a.z); a.w = fmaf(s, b.w, a.w);
}

__device__ inline unsigned short f_to_bf16(float f) {   // round-to-nearest-even
    unsigned u = __float_as_uint(f);
    return (unsigned short)((u + 0x7fffu + ((u >> 16) & 1u)) >> 16);
}
__device__ inline float4 bf16x4_to_f4(uint2 u) {
    float4 r;
    r.x = __uint_as_float(u.x << 16);
    r.y = __uint_as_float(u.x & 0xffff0000u);
    r.z = __uint_as_float(u.y << 16);
    r.w = __uint_as_float(u.y & 0xffff0000u);
    return r;
}

// ---------------------------------------------------------------------------
// Kernel 1 "prep": Qt = PRESCALE*(Q@W_q), Kt = PRESCALE*(K@W_k), VW = bf16(V@W_o).
// grid 1024 x 256 thr, block = 16 rows x 64 cols -> 4 blocks/CU (32 KB LDS).
//   [0,256): Qt  [256,512): Kt  [512,1024): VW
// Single-barrier double-buffered 32-h W tiles, register-prefetched.
// rows stride 260 (pad +4): r-broadcast reads land on 4 distinct banks.
// ---------------------------------------------------------------------------
__global__ __launch_bounds__(256) void prep_kernel(
    const float* __restrict__ Q, const float* __restrict__ K,
    const float* __restrict__ V,
    const float* __restrict__ Wq, const float* __restrict__ Wk,
    const float* __restrict__ Wo,
    float* __restrict__ Qt, float* __restrict__ Kt,
    unsigned short* __restrict__ VW)
{
    __shared__ float rows[16 * 260];     // 16.25 KB (stride-padded)
    __shared__ float wbuf[2][32 * 64];   // 16 KB double buffer
    int tid = threadIdx.x;
    int bid = blockIdx.x;

    const float* X; const float* W;
    int ldW, col0, r0, kind;
    if (bid < 256)      { X=Q; W=Wq; ldW=AA; kind=0; r0=(bid>>1)*16;       col0=(bid&1)*64; }
    else if (bid < 512) { X=K; W=Wk; ldW=AA; kind=1; r0=((bid-256)>>1)*16; col0=((bid-256)&1)*64; }
    else { int b2=bid-512; X=V; W=Wo; ldW=HH; kind=2; r0=(b2>>2)*16;       col0=(b2&3)*64; }

    // stage 16 input rows (4096 floats) into padded LDS
    {
        const float4* Xv = (const float4*)(X + (size_t)r0 * HH);
        #pragma unroll
        for (int it = 0; it < 4; ++it) {
            int l = tid + it * 256;
            int rr = l >> 6, cc = (l & 63) << 2;
            *(float4*)&rows[rr * 260 + cc] = Xv[l];
        }
    }

    // prefetch W chunk 0 (32 h x 64 c = 512 float4, 2 per thread)
    float4 wpf0, wpf1;
    {
        int l0 = tid, l1 = tid + 256;
        wpf0 = *(const float4*)(W + (size_t)(l0 >> 4) * ldW + col0 + ((l0 & 15) << 2));
        wpf1 = *(const float4*)(W + (size_t)(l1 >> 4) * ldW + col0 + ((l1 & 15) << 2));
    }

    int r  = tid >> 4;       // output row 0..15
    int c4 = tid & 15;       // float4 output col
    float4 acc = {0.f, 0.f, 0.f, 0.f};

    for (int c = 0; c < 8; ++c) {
        {   // write prefetched chunk into buf[c&1] (layout = contiguous float4)
            float4* wb = (float4*)&wbuf[c & 1][0];
            wb[tid]       = wpf0;
            wb[tid + 256] = wpf1;
            if (c < 7) {   // issue next chunk's loads (land during compute)
                const float* Wb = W + (size_t)((c + 1) * 32) * ldW + col0;
                int l0 = tid, l1 = tid + 256;
                wpf0 = *(const float4*)(Wb + (size_t)(l0 >> 4) * ldW + ((l0 & 15) << 2));
                wpf1 = *(const float4*)(Wb + (size_t)(l1 >> 4) * ldW + ((l1 & 15) << 2));
            }
        }
        __syncthreads();     // buf[c&1] ready; safe (see dbuf barrier-chain argument)
        const float* rrow = &rows[r * 260 + c * 32];
        const float* wb2  = &wbuf[c & 1][c4 << 2];
        #pragma unroll
        for (int h = 0; h < 32; ++h) {
            float rv  = rrow[h];                          // 4-bank broadcast, conflict-free
            float4 w4 = *(const float4*)(wb2 + h * 64);   // 16-lane b128 + broadcast
            fma4(acc, rv, w4);
        }
    }

    if (kind < 2) {
        float* Y = (kind == 0) ? Qt : Kt;
        acc.x *= PRESCALE; acc.y *= PRESCALE; acc.z *= PRESCALE; acc.w *= PRESCALE;
        *(float4*)(Y + (size_t)(r0 + r) * AA + col0 + (c4 << 2)) = acc;
    } else {
        ushort4 s = { f_to_bf16(acc.x), f_to_bf16(acc.y),
                      f_to_bf16(acc.z), f_to_bf16(acc.w) };
        *(ushort4*)(VW + (size_t)(r0 + r) * HH + col0 + (c4 << 2)) = s;
    }
}

// ---------------------------------------------------------------------------
// Kernel 2 "score_part": raw scores for one (batch, q-pair, k-half).
// grid = 2048 blocks x 256 thr; ~60 VGPR -> 8 waves/SIMD -> 32 waves/CU.
//   score[q][k] = S_all - sum_a 2*v[a] * rcp(2^(Qt[q][a]+Kt[k][a]) + 1)
// Thread = (kl = tid>>4, ag = tid&15 owning 8 a's); q-pair shares one exp2
// via d[j] = 2^(Qt1-Qt0). Next Kt rows register-prefetched. Raw scores are
// written into the weights output region (softepi overwrites them in place).
// ---------------------------------------------------------------------------
__global__ __launch_bounds__(256) void score_part(
    const float* __restrict__ Qt, const float* __restrict__ Kt,
    const float* __restrict__ v,  float* __restrict__ scores)
{
    __shared__ float sc[2][256];         // 2 KB

    int tid = threadIdx.x;
    int bid = blockIdx.x;
    int b    = bid >> 9;                 // 512 blocks per batch
    int rem  = bid & 511;
    int q0   = rem & ~1;                 // q-pair base (rem>>1)*2
    int half = rem & 1;                  // k-half: [256*half, 256*half+256)
    int ag = tid & 15;                   // a-range [8ag, 8ag+8)
    int kl = tid >> 4;                   // k within 16-chunk

    // register caches: Qt row0 (prescaled), d = 2^(q1-q0), 2*v
    float q0r[8], dr[8], v2[8];
    {
        const float4* vp  = (const float4*)(v + ag * 8);
        const float4* qp0 = (const float4*)(Qt + (size_t)(b * SQL + q0)     * AA + ag * 8);
        const float4* qp1 = (const float4*)(Qt + (size_t)(b * SQL + q0 + 1) * AA + ag * 8);
        #pragma unroll
        for (int j4 = 0; j4 < 2; ++j4) {
            float4 vv4 = vp[j4];
            float4 a0  = qp0[j4];
            float4 a1  = qp1[j4];
            *(float4*)&q0r[j4 * 4] = a0;
            dr[j4*4+0] = __builtin_amdgcn_exp2f(a1.x - a0.x);
            dr[j4*4+1] = __builtin_amdgcn_exp2f(a1.y - a0.y);
            dr[j4*4+2] = __builtin_amdgcn_exp2f(a1.z - a0.z);
            dr[j4*4+3] = __builtin_amdgcn_exp2f(a1.w - a0.w);
            v2[j4*4+0] = 2.0f * vv4.x;
            v2[j4*4+1] = 2.0f * vv4.y;
            v2[j4*4+2] = 2.0f * vv4.z;
            v2[j4*4+3] = 2.0f * vv4.w;
        }
    }

    // S_all = sum_a v[a] over all 128 a (xor-reduce the 16 ag-lanes)
    float S_all;
    {
        float ls = 0.f;
        #pragma unroll
        for (int j = 0; j < 8; ++j) ls += v2[j];
        ls += __shfl_xor(ls, 1);
        ls += __shfl_xor(ls, 2);
        ls += __shfl_xor(ls, 4);
        ls += __shfl_xor(ls, 8);
        S_all = 0.5f * ls;
    }

    // main loop: 16 chunks x 16 k-rows, no barriers; next Kt prefetched
    const float4* kp = (const float4*)(Kt + (size_t)(b * SKL + half * 256 + kl) * AA + ag * 8);
    float4 n0 = kp[0], n1 = kp[1];
    for (int c = 0; c < 16; ++c) {
        float kt[8];
        *(float4*)&kt[0] = n0;
        *(float4*)&kt[4] = n1;
        if (c < 15) {
            const float4* np = kp + (size_t)(c + 1) * 16 * (AA / 4);
            n0 = np[0]; n1 = np[1];
        }
        float p0 = 0.f, p1 = 0.f;
        #pragma unroll
        for (int j = 0; j < 8; ++j) {
            float x0 = q0r[j] + kt[j];
            float e0 = __builtin_amdgcn_exp2f(x0);
            float e1 = e0 * dr[j];                  // = 2^(q1+kv)
            float r0 = __builtin_amdgcn_rcpf(e0 + 1.0f);
            float r1 = __builtin_amdgcn_rcpf(e1 + 1.0f);
            p0 = fmaf(v2[j], r0, p0);
            p1 = fmaf(v2[j], r1, p1);
        }
        p0 += __shfl_xor(p0, 1); p1 += __shfl_xor(p1, 1);
        p0 += __shfl_xor(p0, 2); p1 += __shfl_xor(p1, 2);
        p0 += __shfl_xor(p0, 4); p1 += __shfl_xor(p1, 4);
        p0 += __shfl_xor(p0, 8); p1 += __shfl_xor(p1, 8);
        if (ag == 0) {
            sc[0][c * 16 + kl] = S_all - p0;
            sc[1][c * 16 + kl] = S_all - p1;
        }
    }
    __syncthreads();

    if (tid < 128) {    // vectored store of the 2x256 raw scores
        int q = tid >> 6, i = tid & 63;
        float4 val = *(float4*)&sc[q][i << 2];
        *(float4*)(scores + (size_t)(b * SQL + q0 + q) * SKL + half * 256 + (i << 2)) = val;
    }
}

// ---------------------------------------------------------------------------
// Kernel 3 "softepi": softmax (raw->weights, in place) + out = weights@VW + b_o.
// grid = 1024 blocks x 256 thr. Each block owns 2 q-rows: reads its own raw
// scores from the weights region, overwrites them with normalized weights.
// Epilogue: wave w owns k-quarter; bf16 VW read once per block; LDS reduce.
// ---------------------------------------------------------------------------
__global__ __launch_bounds__(256) void softepi_kernel(
    const unsigned short* __restrict__ VW, const float* __restrict__ bo,
    float* __restrict__ weights, float* __restrict__ out)
{
    __shared__ float sw[2][SKL];         // 4 KB
    __shared__ float pout[4][2][HH];     // 8 KB
    __shared__ float pm[2][2], ps[2][2];

    int tid = threadIdx.x;
    int b  = blockIdx.x >> 8;
    int q0 = (blockIdx.x & 255) << 1;
    int wave = tid >> 6, lane = tid & 63;
    int qi = wave & 1, half = wave >> 1;

    // softmax: 4 waves = (row) x (half); raw read straight from global
    {
        float* wrow = weights + (size_t)(b * SQL + q0 + qi) * SKL + half * 256;
        float4 sv = *(float4*)(wrow + (lane << 2));
        float m = fmaxf(fmaxf(sv.x, sv.y), fmaxf(sv.z, sv.w));
        #pragma unroll
        for (int off = 32; off; off >>= 1) m = fmaxf(m, __shfl_xor(m, off));
        if (lane == 0) pm[qi][half] = m;
        __syncthreads();
        float M = fmaxf(pm[qi][0], pm[qi][1]);
        float4 e;
        e.x = __builtin_amdgcn_exp2f((sv.x - M) * 1.44269504f);
        e.y = __builtin_amdgcn_exp2f((sv.y - M) * 1.44269504f);
        e.z = __builtin_amdgcn_exp2f((sv.z - M) * 1.44269504f);
        e.w = __builtin_amdgcn_exp2f((sv.w - M) * 1.44269504f);
        float s = (e.x + e.y) + (e.z + e.w);
        #pragma unroll
        for (int off = 32; off; off >>= 1) s += __shfl_xor(s, off);
        if (lane == 0) ps[qi][half] = s;
        __syncthreads();
        float rinv = 1.0f / (ps[qi][0] + ps[qi][1]);
        float4 w4 = { e.x * rinv, e.y * rinv, e.z * rinv, e.w * rinv };
        *(float4*)&sw[qi][half * 256 + (lane << 2)] = w4;
        *(float4*)(wrow + (lane << 2)) = w4;          // overwrite raw in place
    }
    __syncthreads();

    // epilogue: wave w owns k in [128w, 128w+128); VW is bf16
    {
        const uint2* VWb = (const uint2*)(VW + (size_t)b * SKL * HH);
        float4 a0 = {0,0,0,0}, a1 = {0,0,0,0};
        int kbase = wave * 128;
        #pragma unroll 4
        for (int k = 0; k < 128; ++k) {
            int kk = kbase + k;
            uint2 u = VWb[(size_t)kk * (HH / 4) + lane];   // 8B/lane, coalesced
            float4 vw4 = bf16x4_to_f4(u);
            float w0 = sw[0][kk];                          // wave-uniform broadcast
            float w1 = sw[1][kk];
            fma4(a0, w0, vw4);
            fma4(a1, w1, vw4);
        }
        *(float4*)&pout[wave][0][lane << 2] = a0;
        *(float4*)&pout[wave][1][lane << 2] = a1;
    }
    __syncthreads();
    {
        int h = tid;
        float bias = bo[h];
        #pragma unroll
        for (int q2 = 0; q2 < 2; ++q2) {
            float s = bias + pout[0][q2][h] + pout[1][q2][h]
                           + pout[2][q2][h] + pout[3][q2][h];
            out[(size_t)(b * SQL + q0 + q2) * HH + h] = s;
        }
    }
}

// ---------------------------------------------------------------------------
extern "C" void kernel_launch(void* const* d_in, const int* in_sizes, int n_in,
                              void* d_out, int out_size, void* d_ws, size_t ws_size,
                              hipStream_t stream)
{
    const float* Q  = (const float*)d_in[0];
    const float* K  = (const float*)d_in[1];
    const float* V  = (const float*)d_in[2];
    const float* Wq = (const float*)d_in[3];
    const float* Wk = (const float*)d_in[4];
    const float* v  = (const float*)d_in[5];
    const float* Wo = (const float*)d_in[6];
    const float* bo = (const float*)d_in[7];

    float* out     = (float*)d_out;                   // (B,SQ,H) = 524288
    float* weights = out + (size_t)BB * SQL * HH;     // (B,SQ,SK) = 1048576

    float* Qt = (float*)d_ws;                         // 262144 floats
    float* Kt = Qt + (size_t)BB * SQL * AA;           // 262144 floats
    unsigned short* VW = (unsigned short*)(Kt + (size_t)BB * SKL * AA); // 524288 bf16

    prep_kernel <<<1024, 256, 0, stream>>>(Q, K, V, Wq, Wk, Wo, Qt, Kt, VW);
    score_part  <<<2048, 256, 0, stream>>>(Qt, Kt, v, weights);
    softepi_kernel<<<1024, 256, 0, stream>>>(VW, bo, weights, out);
}

// Round 7
// 130.017 us; speedup vs baseline: 1.0686x; 1.0061x over previous
//
#include <hip/hip_runtime.h>
#include <math.h>

#define BB 4
#define SQL 512
#define SKL 512
#define HH 256
#define AA 128

// 2 * log2(e): Qt/Kt pre-scaled so the score loop feeds v_exp_f32 (2^x) directly.
#define PRESCALE 2.8853900817779268f

__device__ inline void fma4(float4& a, float s, const float4& b) {
    a.x = fmaf(s, b.x, a.x); a.y = fmaf(s, b.y, a.y);
    a.z = fmaf(s, b.z, a.z); a.w = fmaf(s, b.w, a.w);
}

__device__ inline unsigned short f_to_bf16(float f) {   // round-to-nearest-even
    unsigned u = __float_as_uint(f);
    return (unsigned short)((u + 0x7fffu + ((u >> 16) & 1u)) >> 16);
}
__device__ inline float4 bf16x4_to_f4(uint2 u) {
    float4 r;
    r.x = __uint_as_float(u.x << 16);
    r.y = __uint_as_float(u.x & 0xffff0000u);
    r.z = __uint_as_float(u.y << 16);
    r.w = __uint_as_float(u.y & 0xffff0000u);
    return r;
}

// ---------------------------------------------------------------------------
// Kernel 1 "prep": Qt = PRESCALE*(Q@W_q), Kt = PRESCALE*(K@W_k), VW = bf16(V@W_o).
// grid 256 x 256 thr (1 block/CU). Block = 32 rows x 128 cols; thread = 4x4.
//   [0,64): Qt   [64,128): Kt   [128,256): VW (row-tile, col-half)
// Rows live TRANSPOSED in LDS (stride 36: 16B-aligned b128 over 4 rows,
// broadcast across the wave -> conflict-free). W-frag comes DIRECT from
// global (L2-hot, 16B/lane coalesced) with register double-buffer prefetch.
// Per k: 1 ds_read_b128 + 1 global dwordx4 + 16 v_fma  -> VALU/L2-bound,
// ~6x less LDS issue than R6's version (the ~30us LDS-issue wall).
// ---------------------------------------------------------------------------
__global__ __launch_bounds__(256) void prep_kernel(
    const float* __restrict__ Q, const float* __restrict__ K,
    const float* __restrict__ V,
    const float* __restrict__ Wq, const float* __restrict__ Wk,
    const float* __restrict__ Wo,
    float* __restrict__ Qt, float* __restrict__ Kt,
    unsigned short* __restrict__ VW)
{
    __shared__ float rowsT[256 * 36];    // 36 KB, rowsT[k*36 + r]
    int tid = threadIdx.x;
    int bid = blockIdx.x;

    const float* X; const float* W;
    int ldW, col0, r0, kind;
    if (bid < 64)       { X=Q; W=Wq; ldW=AA; kind=0; r0=bid*32;      col0=0; }
    else if (bid < 128) { X=K; W=Wk; ldW=AA; kind=1; r0=(bid-64)*32; col0=0; }
    else { int b2=bid-128; X=V; W=Wo; ldW=HH; kind=2; r0=(b2>>1)*32; col0=(b2&1)*128; }

    // stage 32 input rows transposed: rowsT[k][r]  (write stride 144B = 2-way bank, free)
    {
        const float4* Xv = (const float4*)(X + (size_t)r0 * HH);
        #pragma unroll
        for (int it = 0; it < 8; ++it) {
            int l = tid + it * 256;          // 2048 float4
            int r = l >> 6, k4 = (l & 63) << 2;
            float4 x = Xv[l];
            rowsT[(k4 + 0) * 36 + r] = x.x;
            rowsT[(k4 + 1) * 36 + r] = x.y;
            rowsT[(k4 + 2) * 36 + r] = x.z;
            rowsT[(k4 + 3) * 36 + r] = x.w;
        }
    }

    int mg = tid >> 5;           // 4-row group: rows 4mg..4mg+3
    int n4 = tid & 31;           // float4 col
    int mbase = mg << 2;
    const float* Wg = W + col0 + (n4 << 2);

    float4 acc0 = {0,0,0,0}, acc1 = {0,0,0,0}, acc2 = {0,0,0,0}, acc3 = {0,0,0,0};
    float4 wA[4], wB[4];
    #pragma unroll
    for (int j = 0; j < 4; ++j)
        wA[j] = *(const float4*)(Wg + (size_t)j * ldW);
    __syncthreads();

    for (int g = 0; g < 64; g += 2) {
        #pragma unroll
        for (int j = 0; j < 4; ++j)          // prefetch group g+1
            wB[j] = *(const float4*)(Wg + (size_t)((g + 1) * 4 + j) * ldW);
        {   // compute group g from wA
            float4 a[4];
            #pragma unroll
            for (int j = 0; j < 4; ++j)
                a[j] = *(const float4*)&rowsT[(g * 4 + j) * 36 + mbase];
            #pragma unroll
            for (int j = 0; j < 4; ++j) {
                fma4(acc0, a[j].x, wA[j]);
                fma4(acc1, a[j].y, wA[j]);
                fma4(acc2, a[j].z, wA[j]);
                fma4(acc3, a[j].w, wA[j]);
            }
        }
        if (g + 2 < 64) {
            #pragma unroll
            for (int j = 0; j < 4; ++j)      // prefetch group g+2
                wA[j] = *(const float4*)(Wg + (size_t)((g + 2) * 4 + j) * ldW);
        }
        {   // compute group g+1 from wB
            float4 a[4];
            #pragma unroll
            for (int j = 0; j < 4; ++j)
                a[j] = *(const float4*)&rowsT[((g + 1) * 4 + j) * 36 + mbase];
            #pragma unroll
            for (int j = 0; j < 4; ++j) {
                fma4(acc0, a[j].x, wB[j]);
                fma4(acc1, a[j].y, wB[j]);
                fma4(acc2, a[j].z, wB[j]);
                fma4(acc3, a[j].w, wB[j]);
            }
        }
    }

    if (kind < 2) {
        float* Y = (kind == 0) ? Qt : Kt;
        float4 av[4] = {acc0, acc1, acc2, acc3};
        #pragma unroll
        for (int i = 0; i < 4; ++i) {
            float4 s = av[i];
            s.x *= PRESCALE; s.y *= PRESCALE; s.z *= PRESCALE; s.w *= PRESCALE;
            *(float4*)(Y + (size_t)(r0 + mbase + i) * AA + (n4 << 2)) = s;
        }
    } else {
        float4 av[4] = {acc0, acc1, acc2, acc3};
        #pragma unroll
        for (int i = 0; i < 4; ++i) {
            ushort4 s = { f_to_bf16(av[i].x), f_to_bf16(av[i].y),
                          f_to_bf16(av[i].z), f_to_bf16(av[i].w) };
            *(ushort4*)(VW + (size_t)(r0 + mbase + i) * HH + col0 + (n4 << 2)) = s;
        }
    }
}

// ---------------------------------------------------------------------------
// Kernel 2 "score_part": raw scores for one (batch, q-pair, k-half).
// grid = 2048 blocks x 256 thr; ~48 VGPR -> 32 waves/CU.
//   score[q][k] = S_all - sum_a 2*v[a] * rcp(2^(Qt[q][a]+Kt[k][a]) + 1)
// Thread = (kl = tid>>4, ag = tid&15 owning 8 a's); q-pair shares one exp2
// via d[j] = 2^(Qt1-Qt0). Next Kt rows register-prefetched. Raw scores are
// written into the weights output region (softepi overwrites them in place).
// ---------------------------------------------------------------------------
__global__ __launch_bounds__(256) void score_part(
    const float* __restrict__ Qt, const float* __restrict__ Kt,
    const float* __restrict__ v,  float* __restrict__ scores)
{
    __shared__ float sc[2][256];         // 2 KB

    int tid = threadIdx.x;
    int bid = blockIdx.x;
    int b    = bid >> 9;                 // 512 blocks per batch
    int rem  = bid & 511;
    int q0   = rem & ~1;                 // q-pair base
    int half = rem & 1;                  // k-half: [256*half, 256*half+256)
    int ag = tid & 15;                   // a-range [8ag, 8ag+8)
    int kl = tid >> 4;                   // k within 16-chunk

    float q0r[8], dr[8], v2[8];
    {
        const float4* vp  = (const float4*)(v + ag * 8);
        const float4* qp0 = (const float4*)(Qt + (size_t)(b * SQL + q0)     * AA + ag * 8);
        const float4* qp1 = (const float4*)(Qt + (size_t)(b * SQL + q0 + 1) * AA + ag * 8);
        #pragma unroll
        for (int j4 = 0; j4 < 2; ++j4) {
            float4 vv4 = vp[j4];
            float4 a0  = qp0[j4];
            float4 a1  = qp1[j4];
            *(float4*)&q0r[j4 * 4] = a0;
            dr[j4*4+0] = __builtin_amdgcn_exp2f(a1.x - a0.x);
            dr[j4*4+1] = __builtin_amdgcn_exp2f(a1.y - a0.y);
            dr[j4*4+2] = __builtin_amdgcn_exp2f(a1.z - a0.z);
            dr[j4*4+3] = __builtin_amdgcn_exp2f(a1.w - a0.w);
            v2[j4*4+0] = 2.0f * vv4.x;
            v2[j4*4+1] = 2.0f * vv4.y;
            v2[j4*4+2] = 2.0f * vv4.z;
            v2[j4*4+3] = 2.0f * vv4.w;
        }
    }

    float S_all;
    {
        float ls = 0.f;
        #pragma unroll
        for (int j = 0; j < 8; ++j) ls += v2[j];
        ls += __shfl_xor(ls, 1);
        ls += __shfl_xor(ls, 2);
        ls += __shfl_xor(ls, 4);
        ls += __shfl_xor(ls, 8);
        S_all = 0.5f * ls;
    }

    const float4* kp = (const float4*)(Kt + (size_t)(b * SKL + half * 256 + kl) * AA + ag * 8);
    float4 n0 = kp[0], n1 = kp[1];
    for (int c = 0; c < 16; ++c) {
        float kt[8];
        *(float4*)&kt[0] = n0;
        *(float4*)&kt[4] = n1;
        if (c < 15) {
            const float4* np = kp + (size_t)(c + 1) * 16 * (AA / 4);
            n0 = np[0]; n1 = np[1];
        }
        float p0 = 0.f, p1 = 0.f;
        #pragma unroll
        for (int j = 0; j < 8; ++j) {
            float x0 = q0r[j] + kt[j];
            float e0 = __builtin_amdgcn_exp2f(x0);
            float e1 = e0 * dr[j];                  // = 2^(q1+kv)
            float r0 = __builtin_amdgcn_rcpf(e0 + 1.0f);
            float r1 = __builtin_amdgcn_rcpf(e1 + 1.0f);
            p0 = fmaf(v2[j], r0, p0);
            p1 = fmaf(v2[j], r1, p1);
        }
        p0 += __shfl_xor(p0, 1); p1 += __shfl_xor(p1, 1);
        p0 += __shfl_xor(p0, 2); p1 += __shfl_xor(p1, 2);
        p0 += __shfl_xor(p0, 4); p1 += __shfl_xor(p1, 4);
        p0 += __shfl_xor(p0, 8); p1 += __shfl_xor(p1, 8);
        if (ag == 0) {
            sc[0][c * 16 + kl] = S_all - p0;
            sc[1][c * 16 + kl] = S_all - p1;
        }
    }
    __syncthreads();

    if (tid < 128) {    // vectored store of the 2x256 raw scores
        int q = tid >> 6, i = tid & 63;
        float4 val = *(float4*)&sc[q][i << 2];
        *(float4*)(scores + (size_t)(b * SQL + q0 + q) * SKL + half * 256 + (i << 2)) = val;
    }
}

// ---------------------------------------------------------------------------
// Kernel 3 "softepi": softmax (raw->weights, in place) + out = weights@VW + b_o.
// grid = 512 blocks x 256 thr. Block = (batch, 4 q-rows): halves the VW L2
// traffic vs the R6 2-row version. Softmax: wave qi owns row qi fully (pure
// in-wave reduction). Epilogue: wave w owns k-quarter, weights read as b128
// wave-uniform broadcasts; bf16 VW; LDS tree-reduce over waves.
// ---------------------------------------------------------------------------
__global__ __launch_bounds__(256) void softepi_kernel(
    const unsigned short* __restrict__ VW, const float* __restrict__ bo,
    float* __restrict__ weights, float* __restrict__ out)
{
    __shared__ float sw[4][SKL];         // 8 KB
    __shared__ float pout[4][4][HH];     // 16 KB

    int tid = threadIdx.x;
    int b  = blockIdx.x >> 7;            // 128 blocks per batch
    int q0 = (blockIdx.x & 127) << 2;    // 4 q-rows
    int wave = tid >> 6, lane = tid & 63;

    // ---- softmax: wave qi handles row q0+qi (512 k = 2 float4 per lane)
    {
        float* wrow = weights + (size_t)(b * SQL + q0 + wave) * SKL;
        float4 s0 = *(float4*)(wrow + (lane << 2));
        float4 s1 = *(float4*)(wrow + 256 + (lane << 2));
        float m = fmaxf(fmaxf(fmaxf(s0.x, s0.y), fmaxf(s0.z, s0.w)),
                        fmaxf(fmaxf(s1.x, s1.y), fmaxf(s1.z, s1.w)));
        #pragma unroll
        for (int off = 32; off; off >>= 1) m = fmaxf(m, __shfl_xor(m, off));
        float4 e0, e1;
        e0.x = __builtin_amdgcn_exp2f((s0.x - m) * 1.44269504f);
        e0.y = __builtin_amdgcn_exp2f((s0.y - m) * 1.44269504f);
        e0.z = __builtin_amdgcn_exp2f((s0.z - m) * 1.44269504f);
        e0.w = __builtin_amdgcn_exp2f((s0.w - m) * 1.44269504f);
        e1.x = __builtin_amdgcn_exp2f((s1.x - m) * 1.44269504f);
        e1.y = __builtin_amdgcn_exp2f((s1.y - m) * 1.44269504f);
        e1.z = __builtin_amdgcn_exp2f((s1.z - m) * 1.44269504f);
        e1.w = __builtin_amdgcn_exp2f((s1.w - m) * 1.44269504f);
        float s = ((e0.x + e0.y) + (e0.z + e0.w)) + ((e1.x + e1.y) + (e1.z + e1.w));
        #pragma unroll
        for (int off = 32; off; off >>= 1) s += __shfl_xor(s, off);
        float rinv = 1.0f / s;
        float4 w0 = { e0.x * rinv, e0.y * rinv, e0.z * rinv, e0.w * rinv };
        float4 w1 = { e1.x * rinv, e1.y * rinv, e1.z * rinv, e1.w * rinv };
        *(float4*)&sw[wave][lane << 2]         = w0;
        *(float4*)&sw[wave][256 + (lane << 2)] = w1;
        *(float4*)(wrow + (lane << 2))       = w0;
        *(float4*)(wrow + 256 + (lane << 2)) = w1;
    }
    __syncthreads();

    // ---- epilogue: wave w owns k in [128w, 128w+128); VW bf16, weights b128
    {
        const uint2* VWb = (const uint2*)(VW + (size_t)b * SKL * HH);
        float4 a0 = {0,0,0,0}, a1 = {0,0,0,0}, a2 = {0,0,0,0}, a3 = {0,0,0,0};
        int kbase = wave * 128;
        for (int k4 = 0; k4 < 32; ++k4) {
            int kk = kbase + k4 * 4;
            float4 w0 = *(const float4*)&sw[0][kk];   // wave-uniform b128 broadcasts
            float4 w1 = *(const float4*)&sw[1][kk];
            float4 w2 = *(const float4*)&sw[2][kk];
            float4 w3 = *(const float4*)&sw[3][kk];
            #pragma unroll
            for (int j = 0; j < 4; ++j) {
                uint2 u = VWb[(size_t)(kk + j) * (HH / 4) + lane];   // 8B/lane coalesced
                float4 vw4 = bf16x4_to_f4(u);
                fma4(a0, ((const float*)&w0)[j], vw4);
                fma4(a1, ((const float*)&w1)[j], vw4);
                fma4(a2, ((const float*)&w2)[j], vw4);
                fma4(a3, ((const float*)&w3)[j], vw4);
            }
        }
        *(float4*)&pout[wave][0][lane << 2] = a0;
        *(float4*)&pout[wave][1][lane << 2] = a1;
        *(float4*)&pout[wave][2][lane << 2] = a2;
        *(float4*)&pout[wave][3][lane << 2] = a3;
    }
    __syncthreads();
    {
        int h = tid;
        float bias = bo[h];
        #pragma unroll
        for (int q2 = 0; q2 < 4; ++q2) {
            float s = bias + pout[0][q2][h] + pout[1][q2][h]
                           + pout[2][q2][h] + pout[3][q2][h];
            out[(size_t)(b * SQL + q0 + q2) * HH + h] = s;
        }
    }
}

// ---------------------------------------------------------------------------
extern "C" void kernel_launch(void* const* d_in, const int* in_sizes, int n_in,
                              void* d_out, int out_size, void* d_ws, size_t ws_size,
                              hipStream_t stream)
{
    const float* Q  = (const float*)d_in[0];
    const float* K  = (const float*)d_in[1];
    const float* V  = (const float*)d_in[2];
    const float* Wq = (const float*)d_in[3];
    const float* Wk = (const float*)d_in[4];
    const float* v  = (const float*)d_in[5];
    const float* Wo = (const float*)d_in[6];
    const float* bo = (const float*)d_in[7];

    float* out     = (float*)d_out;                   // (B,SQ,H) = 524288
    float* weights = out + (size_t)BB * SQL * HH;     // (B,SQ,SK) = 1048576

    float* Qt = (float*)d_ws;                         // 262144 floats
    float* Kt = Qt + (size_t)BB * SQL * AA;           // 262144 floats
    unsigned short* VW = (unsigned short*)(Kt + (size_t)BB * SKL * AA); // 524288 bf16

    prep_kernel  <<<256, 256, 0, stream>>>(Q, K, V, Wq, Wk, Wo, Qt, Kt, VW);
    score_part   <<<2048, 256, 0, stream>>>(Qt, Kt, v, weights);
    softepi_kernel<<<512, 256, 0, stream>>>(VW, bo, weights, out);
}